// Round 5
// baseline (498.560 us; speedup 1.0000x reference)
//
#include <hip/hip_runtime.h>
#include <math.h>

constexpr float DECAY = 0.99f;
constexpr float EPS_F = 1e-5f;
constexpr float MARGIN = 0.08f;   // bf16-split worst-case err ~0.02/side; 2x safety

typedef short bf16x8 __attribute__((ext_vector_type(8)));
typedef float f32x4 __attribute__((ext_vector_type(4)));

#define BM 128      // rows per block
#define KSPLIT 2    // K/KSPLIT codes scanned per block
#define NU 128      // units per block: 32 kt x 4 du (unit = 64 col x 64 d)
#define D_FIX 256

__device__ __forceinline__ unsigned rne_bf16(float f) {
  unsigned u = __float_as_uint(f);
  return (u + 0x7fffu + ((u >> 16) & 1u)) >> 16;
}
// split f32 -> hi (truncated top16) | lo (RNE bf16 of remainder), packed in u32
__device__ __forceinline__ unsigned pack_hilo(float v) {
  unsigned u = __float_as_uint(v);
  unsigned hi = u & 0xffff0000u;
  float rem = v - __uint_as_float(hi);
  return hi | rne_bf16(rem);
}

// ---------------- kernel 0: prepack E into unit-tiled swizzled bf16 hi/lo planes
// unit = (ct, du): cols ct*64..+63, d du*64..+63.  16KB per unit: h[4096]+l[4096] ushorts.
// within plane: pos = col*64 + ((dl>>3) ^ (col&7))*8 + (dl&7)
__global__ void k_prepack(const float* __restrict__ e, ushort* __restrict__ phl, int K) {
  __shared__ ushort tile[8192];
  const int unit = blockIdx.x;
  const int ct = unit >> 2, du = unit & 3;
  const int t = threadIdx.x;
#pragma unroll
  for (int p = 0; p < 16; ++p) {
    int idx = t + p * 256;
    int dl = idx >> 6, col = idx & 63;
    float v = e[(size_t)(du * 64 + dl) * K + ct * 64 + col];
    unsigned pk = pack_hilo(v);
    int pos = col * 64 + (((dl >> 3) ^ (col & 7)) << 3) + (dl & 7);
    tile[pos] = (ushort)(pk >> 16);
    tile[4096 + pos] = (ushort)(pk & 0xffffu);
  }
  __syncthreads();
  uint4* dst = (uint4*)(phl + (size_t)unit * 8192);
  const uint4* srcT = (const uint4*)tile;
#pragma unroll
  for (int p = 0; p < 4; ++p) dst[t + p * 256] = srcT[t + p * 256];
}

// ---------------- kernel 1: e2[k] = sum_d e[d,k]^2  (f64 exact + f32 copy)
__global__ void k_enorm(const float* __restrict__ e, double* __restrict__ e2d,
                        float* __restrict__ e2f, int D, int K) {
  __shared__ double red[4][64];
  const int kl = threadIdx.x & 63;
  const int part = threadIdx.x >> 6;
  const int k = blockIdx.x * 64 + kl;
  double s = 0.0;
  for (int d = part; d < D; d += 4) {
    double v = (double)e[(size_t)d * K + k];
    s = fma(v, v, s);
  }
  red[part][kl] = s;
  __syncthreads();
  if (part == 0) {
    double t = ((red[0][kl] + red[1][kl]) + red[2][kl]) + red[3][kl];
    e2d[k] = t;
    e2f[k] = (float)t;
  }
}

// ---------------- kernel 2: MFMA bf16-split top-2 argmin over a K-slice
__launch_bounds__(256, 2)
__global__ void k_argmin_mfma(const float* __restrict__ x, const ushort* __restrict__ phl,
                              const float* __restrict__ e2f,
                              float* __restrict__ bestv, float* __restrict__ secv,
                              int* __restrict__ besti, int N, int K) {
  __shared__ ushort es[2][8192];   // 16KB/buf: h-plane[4096] + l-plane[4096]
  __shared__ float e2s[2048];

  const int tid = threadIdx.x;
  const int w   = tid >> 6;        // wave 0..3
  const int l   = tid & 63;
  const int g   = l >> 4;          // lane group 0..3
  const int c16 = l & 15;
  const int kbase = blockIdx.y * (K / KSPLIT);
  const int rowW  = blockIdx.x * BM + w * 32;

  char* esb = (char*)es;

#define STAGE(u_, b_) do {                                                          \
    const char* gs_ = (const char*)phl +                                            \
        (((size_t)blockIdx.y * NU + (size_t)(u_)) << 14) + (w << 12) + (l << 4);    \
    char* ld_ = esb + ((b_) << 14) + (w << 12);                                     \
    __builtin_amdgcn_global_load_lds((const unsigned*)(gs_),        (unsigned*)(ld_),        16, 0, 0); \
    __builtin_amdgcn_global_load_lds((const unsigned*)(gs_ + 1024), (unsigned*)(ld_ + 1024), 16, 0, 0); \
    __builtin_amdgcn_global_load_lds((const unsigned*)(gs_ + 2048), (unsigned*)(ld_ + 2048), 16, 0, 0); \
    __builtin_amdgcn_global_load_lds((const unsigned*)(gs_ + 3072), (unsigned*)(ld_ + 3072), 16, 0, 0); \
  } while (0)

  STAGE(0, 0);   // prefetch unit 0 while we pack X

  // stage e2 slice (2048 codes)
  for (int i = tid; i < 2048; i += 256) e2s[i] = e2f[kbase + i];

  // ---- X fragments in registers: rows rowW + m*16 + c16, d = t*32 + 8g + 0..7
  bf16x8 xh[2][8], xl[2][8];
#pragma unroll
  for (int m = 0; m < 2; ++m) {
    const float* xr = x + (size_t)(rowW + m * 16 + c16) * D_FIX + 8 * g;
#pragma unroll
    for (int t = 0; t < 8; ++t) {
      float4 fa = *(const float4*)(xr + t * 32);
      float4 fb = *(const float4*)(xr + t * 32 + 4);
      float f[8] = {fa.x, fa.y, fa.z, fa.w, fb.x, fb.y, fb.z, fb.w};
      union { unsigned u[4]; bf16x8 v; } H, L;
#pragma unroll
      for (int p = 0; p < 4; ++p) {
        unsigned w0 = pack_hilo(f[2 * p]);
        unsigned w1 = pack_hilo(f[2 * p + 1]);
        H.u[p] = (w0 >> 16) | (w1 & 0xffff0000u);
        L.u[p] = (w0 & 0xffffu) | (w1 << 16);
      }
      xh[m][t] = H.v;
      xl[m][t] = L.v;
    }
  }

  float best[2][4], sec[2][4];
  int bidx[2][4];
#pragma unroll
  for (int m = 0; m < 2; ++m)
#pragma unroll
    for (int r = 0; r < 4; ++r) { best[m][r] = 3e38f; sec[m][r] = 3e38f; bidx[m][r] = 0; }

  // per-thread swizzle base: chunk'(tt,g,col) = (4tt+g) ^ (col&7), col&7 == c16&7
  const int sw16 = ((g ^ (c16 & 7)) << 4);    // byte offset at tt=0
  const char* thr0 = esb + c16 * 128;

  f32x4 acc[2][4];

  for (int u = 0; u < NU; ++u) {
    __syncthreads();                     // drains pending global_load_lds (vmcnt 0)
    if (u + 1 < NU) STAGE(u + 1, (u + 1) & 1);
    const int kt = u >> 2, du = u & 3;

    if (du == 0) {
#pragma unroll
      for (int m = 0; m < 2; ++m)
#pragma unroll
        for (int c = 0; c < 4; ++c) acc[m][c] = (f32x4){0.f, 0.f, 0.f, 0.f};
    }

    const char* pbuf = thr0 + ((u & 1) << 14);
#pragma unroll
    for (int tt = 0; tt < 2; ++tt) {
      const int t = 2 * du + tt;
      const char* pt = pbuf + (sw16 ^ (tt << 6));
#pragma unroll
      for (int c = 0; c < 4; ++c) {
        bf16x8 bh = *(const bf16x8*)(pt + c * 2048);
        bf16x8 bl = *(const bf16x8*)(pt + c * 2048 + 8192);
#pragma unroll
        for (int m = 0; m < 2; ++m) {
          acc[m][c] = __builtin_amdgcn_mfma_f32_16x16x32_bf16(xh[m][t], bh, acc[m][c], 0, 0, 0);
          acc[m][c] = __builtin_amdgcn_mfma_f32_16x16x32_bf16(xh[m][t], bl, acc[m][c], 0, 0, 0);
          acc[m][c] = __builtin_amdgcn_mfma_f32_16x16x32_bf16(xl[m][t], bh, acc[m][c], 0, 0, 0);
        }
      }
    }

    if (du == 3) {
      // fold k-tile into running top-2 (k ascending => strict < keeps smallest k)
#pragma unroll
      for (int c = 0; c < 4; ++c) {
        const int klocal = kt * 64 + c * 16 + c16;
        const float e2v = e2s[klocal];
        const int kg = kbase + klocal;
#pragma unroll
        for (int m = 0; m < 2; ++m)
#pragma unroll
          for (int r = 0; r < 4; ++r) {
            float dist = fmaf(-2.f, acc[m][c][r], e2v);
            if (dist < best[m][r]) { sec[m][r] = best[m][r]; best[m][r] = dist; bidx[m][r] = kg; }
            else sec[m][r] = fminf(sec[m][r], dist);
          }
      }
    }
  }
#undef STAGE

  // merge top-2 across the 16 col lanes (same row)
#pragma unroll
  for (int off = 1; off < 16; off <<= 1) {
#pragma unroll
    for (int m = 0; m < 2; ++m)
#pragma unroll
      for (int r = 0; r < 4; ++r) {
        float ob = __shfl_xor(best[m][r], off);
        float os = __shfl_xor(sec[m][r], off);
        int   oi = __shfl_xor(bidx[m][r], off);
        if (ob < best[m][r] || (ob == best[m][r] && oi < bidx[m][r])) {
          sec[m][r] = fminf(best[m][r], os); best[m][r] = ob; bidx[m][r] = oi;
        } else {
          sec[m][r] = fminf(sec[m][r], ob);
        }
      }
  }

  if (c16 == 0) {
    const size_t base = (size_t)blockIdx.y * N;
#pragma unroll
    for (int m = 0; m < 2; ++m)
#pragma unroll
      for (int r = 0; r < 4; ++r) {
        int row = rowW + m * 16 + 4 * g + r;
        bestv[base + row] = best[m][r];
        secv[base + row]  = sec[m][r];
        besti[base + row] = bidx[m][r];
      }
  }
}

// ---------------- kernel 3: combine K-slices, flag ambiguous rows
__global__ void k_combine(const float* __restrict__ bestv, const float* __restrict__ secv,
                          const int* __restrict__ besti, int* __restrict__ idx_out,
                          int* __restrict__ list, unsigned int* __restrict__ count, int N) {
  int n = blockIdx.x * blockDim.x + threadIdx.x;
  if (n >= N) return;
  float b = bestv[n], s = secv[n];
  int bi = besti[n];
#pragma unroll
  for (int p = 1; p < KSPLIT; ++p) {
    float ob = bestv[(size_t)p * N + n];
    float os = secv[(size_t)p * N + n];
    int   oi = besti[(size_t)p * N + n];
    if (ob < b || (ob == b && oi < bi)) { s = fminf(b, os); b = ob; bi = oi; }
    else s = fminf(s, ob);
  }
  idx_out[n] = bi;
  if (s - b < MARGIN) {
    unsigned int p = atomicAdd(count, 1u);
    list[p] = n;
  }
}

// ---------------- kernel 4: exact f64 rescan of flagged rows (throughput form)
__launch_bounds__(256, 4)
__global__ void k_rescan(const float* __restrict__ x, const float* __restrict__ e,
                         const double* __restrict__ e2d, const int* __restrict__ list,
                         const unsigned int* __restrict__ count, int* __restrict__ idx_out,
                         int K) {
  __shared__ double xrow[D_FIX];
  __shared__ double rv[256];
  __shared__ int ri[256];
  const int tid = threadIdx.x;
  const unsigned int cnt = *count;
  for (unsigned int ii = blockIdx.x; ii < cnt; ii += gridDim.x) {
    const int row = list[ii];
    __syncthreads();
    xrow[tid] = (double)x[(size_t)row * D_FIX + tid];
    __syncthreads();
    double bb = 1e300; int bi = 0;
    for (int j = 0; j < K; j += 256) {
      const int k = j + tid;
      const float* ek = e + k;
      double a0 = 0.0, a1 = 0.0, a2 = 0.0, a3 = 0.0;
#pragma unroll 8
      for (int d = 0; d < D_FIX; d += 4) {
        a0 = fma(xrow[d + 0], (double)ek[(size_t)(d + 0) * K], a0);
        a1 = fma(xrow[d + 1], (double)ek[(size_t)(d + 1) * K], a1);
        a2 = fma(xrow[d + 2], (double)ek[(size_t)(d + 2) * K], a2);
        a3 = fma(xrow[d + 3], (double)ek[(size_t)(d + 3) * K], a3);
      }
      double dist = e2d[k] - 2.0 * ((a0 + a1) + (a2 + a3));
      if (dist < bb || (dist == bb && k < bi)) { bb = dist; bi = k; }
    }
    rv[tid] = bb; ri[tid] = bi;
    __syncthreads();
    for (int off = 128; off > 0; off >>= 1) {
      if (tid < off) {
        if (rv[tid + off] < rv[tid] || (rv[tid + off] == rv[tid] && ri[tid + off] < ri[tid])) {
          rv[tid] = rv[tid + off]; ri[tid] = ri[tid + off];
        }
      }
      __syncthreads();
    }
    if (tid == 0) idx_out[row] = ri[0];
    __syncthreads();
  }
}

// ---------------- kernel 5: histogram + float indices
__global__ void k_hist(const int* __restrict__ idx, unsigned int* __restrict__ cnt,
                       float* __restrict__ idxf_out, int N) {
  int n = blockIdx.x * blockDim.x + threadIdx.x;
  if (n >= N) return;
  int c = idx[n];
  idxf_out[n] = (float)c;
  atomicAdd(&cnt[c], 1u);
}

// ---------------- kernel 6: cluster_size_new, n, smoothed cs
__global__ void k_cluster(const float* __restrict__ cs_in,
                          const unsigned int* __restrict__ cnt,
                          float* __restrict__ out_csn, float* __restrict__ cs_ws,
                          int K) {
  __shared__ double red[256];
  const int tid = threadIdx.x;
  double s = 0.0;
  for (int k = tid; k < K; k += 256) {
    float csn = cs_in[k] * DECAY + (float)cnt[k] * (1.0f - EPS_F);
    out_csn[k] = csn;
    s += (double)csn;
  }
  red[tid] = s;
  __syncthreads();
  for (int off = 128; off > 0; off >>= 1) {
    if (tid < off) red[tid] += red[tid + off];
    __syncthreads();
  }
  const float n = (float)red[0];
  const float denom = n + (float)K * EPS_F;
  for (int k = tid; k < K; k += 256) {
    float csn = out_csn[k];
    cs_ws[k] = (csn + EPS_F) / denom * n;
  }
}

// ---------------- kernel 7: embed_avg_new = avg*decay ; embed_new = avg_new / cs
__global__ void k_embed(const float* __restrict__ avg_in, const float* __restrict__ cs_ws,
                        float* __restrict__ out_avg, float* __restrict__ out_emb, int K) {
  int k = blockIdx.x * blockDim.x + threadIdx.x;
  int d = blockIdx.y;
  if (k >= K) return;
  size_t i = (size_t)d * K + k;
  float a = avg_in[i] * DECAY;
  out_avg[i] = a;
  out_emb[i] = a / cs_ws[k];
}

// ---------------- kernel 8: transpose out_emb [D][K] -> embT [K][D]
__global__ void k_transpose(const float* __restrict__ src, float* __restrict__ dst,
                            int D, int K) {
  __shared__ float t[64][65];
  const int kb = blockIdx.x * 64;
  const int db = blockIdx.y * 64;
  const int c = threadIdx.x & 63;
  const int r0 = (threadIdx.x >> 6) * 16;
  for (int i = 0; i < 16; ++i)
    t[r0 + i][c] = src[(size_t)(db + r0 + i) * K + kb + c];
  __syncthreads();
  for (int i = 0; i < 16; ++i)
    dst[(size_t)(kb + r0 + i) * D + db + c] = t[c][r0 + i];
}

// ---------------- kernel 9: gather quantize + straight-through + diff partial
__global__ void k_gather(const float* __restrict__ x, const float* __restrict__ embT,
                         const int* __restrict__ idx, float* __restrict__ out_q,
                         float* __restrict__ partial) {
  __shared__ float red[256];
  const int tid = threadIdx.x;
  const int n0 = blockIdx.x * 64;
  float s = 0.f;
  for (int u = 0; u < 16; ++u) {
    int i = u * 256 + tid;
    int row = n0 + (i >> 6);
    int f4 = (i & 63) * 4;
    int code = idx[row];
    float4 q  = *(const float4*)&embT[(size_t)code * D_FIX + f4];
    float4 xv = *(const float4*)&x[(size_t)row * D_FIX + f4];
    float4 dv = {q.x - xv.x, q.y - xv.y, q.z - xv.z, q.w - xv.w};
    float4 val = {xv.x + dv.x, xv.y + dv.y, xv.z + dv.z, xv.w + dv.w};
    *(float4*)&out_q[(size_t)row * D_FIX + f4] = val;
    s += dv.x * dv.x + dv.y * dv.y + dv.z * dv.z + dv.w * dv.w;
  }
  red[tid] = s;
  __syncthreads();
  for (int off = 128; off > 0; off >>= 1) {
    if (tid < off) red[tid] += red[tid + off];
    __syncthreads();
  }
  if (tid == 0) partial[blockIdx.x] = red[0];
}

// ---------------- kernel 10: diff = mean
__global__ void k_diff(const float* __restrict__ partial, float* __restrict__ out_diff,
                       int NB, long long total) {
  __shared__ double red[256];
  const int tid = threadIdx.x;
  double s = 0.0;
  for (int i = tid; i < NB; i += 256) s += (double)partial[i];
  red[tid] = s;
  __syncthreads();
  for (int off = 128; off > 0; off >>= 1) {
    if (tid < off) red[tid] += red[tid + off];
    __syncthreads();
  }
  if (tid == 0) out_diff[0] = (float)(red[0] / (double)total);
}

extern "C" void kernel_launch(void* const* d_in, const int* in_sizes, int n_in,
                              void* d_out, int out_size, void* d_ws, size_t ws_size,
                              hipStream_t stream) {
  const float* x            = (const float*)d_in[0];
  const float* embed        = (const float*)d_in[1];
  const float* cluster_size = (const float*)d_in[2];
  const float* embed_avg    = (const float*)d_in[3];

  const int K = in_sizes[2];
  const int D = in_sizes[1] / K;      // 256
  const int N = in_sizes[0] / D;      // 32768

  float* out      = (float*)d_out;
  float* out_q    = out;                          // N*D
  float* out_idx  = out_q + (size_t)N * D;        // N (indices as float)
  float* out_diff = out_idx + N;                  // 1
  float* out_csn  = out_diff + 1;                 // K
  float* out_avg  = out_csn + K;                  // D*K
  float* out_emb  = out_avg + (size_t)D * K;      // D*K

  char* ws = (char*)d_ws;
  double*       e2d     = (double*)ws;               ws += (size_t)K * 8;
  float*        e2f     = (float*)ws;                ws += (size_t)K * 4;
  int*          idx     = (int*)ws;                  ws += (size_t)N * 4;
  unsigned int* cnt     = (unsigned int*)ws;         ws += (size_t)K * 4;
  float*        cs_ws   = (float*)ws;                ws += (size_t)K * 4;
  float*        partial = (float*)ws;                ws += (size_t)(N / 64) * 4;
  float*        bestv   = (float*)ws;                ws += (size_t)KSPLIT * N * 4;
  float*        secv    = (float*)ws;                ws += (size_t)KSPLIT * N * 4;
  int*          besti   = (int*)ws;                  ws += (size_t)KSPLIT * N * 4;
  int*          list    = (int*)ws;                  ws += (size_t)N * 4;
  unsigned int* count   = (unsigned int*)ws;         ws += 64;
  float*        embT    = (float*)ws;                ws += (size_t)K * D * 4;
  ushort*       phl     = (ushort*)ws;               ws += (size_t)K * D * 4;  // 4MB

  hipMemsetAsync(cnt, 0, (size_t)K * sizeof(unsigned int), stream);
  hipMemsetAsync(count, 0, sizeof(unsigned int), stream);

  k_prepack<<<dim3((K / 64) * 4), dim3(256), 0, stream>>>(embed, phl, K);
  k_enorm<<<dim3(K / 64), dim3(256), 0, stream>>>(embed, e2d, e2f, D, K);
  k_argmin_mfma<<<dim3(N / BM, KSPLIT), dim3(256), 0, stream>>>(x, phl, e2f, bestv, secv,
                                                                besti, N, K);
  k_combine<<<dim3((N + 255) / 256), dim3(256), 0, stream>>>(bestv, secv, besti, idx,
                                                             list, count, N);
  k_rescan<<<dim3(1024), dim3(256), 0, stream>>>(x, embed, e2d, list, count, idx, K);
  k_hist<<<dim3((N + 255) / 256), dim3(256), 0, stream>>>(idx, cnt, out_idx, N);
  k_cluster<<<dim3(1), dim3(256), 0, stream>>>(cluster_size, cnt, out_csn, cs_ws, K);
  k_embed<<<dim3((K + 255) / 256, D), dim3(256), 0, stream>>>(embed_avg, cs_ws, out_avg, out_emb, K);
  k_transpose<<<dim3(K / 64, D / 64), dim3(256), 0, stream>>>(out_emb, embT, D, K);
  k_gather<<<dim3(N / 64), dim3(256), 0, stream>>>(x, embT, idx, out_q, partial);
  k_diff<<<dim3(1), dim3(256), 0, stream>>>(partial, out_diff, N / 64, (long long)N * D);
}